// Round 3
// baseline (210.532 us; speedup 1.0000x reference)
//
#include <hip/hip_runtime.h>
#include <cfloat>

#define B_ 64
#define S_ 64
#define F_ 512
#define E_ 1024
#define D_ 1024
#define FT_ 32           // f-rows per tile
#define NT_ (F_ / FT_)   // 16 tiles per b

// ---------------------------------------------------------------------------
// Kernel 1 (flash-style): per (b, tile) block of 256 threads:
//   phase 1: s_row[f] = dot(features[b,f0+f,:], W_f)   (wave-per-row, shfl)
//   local softmax: m_t = max s_row, sw[f] = exp(s_row-m_t), s_t = sum sw
//   phase 2: part[b,t,d] = sum_f sw[f] * features[b,f0+f,d]
// The tile (128 KB) is read once from HBM in phase 1 and re-read from the
// same CU's L1/L2 in phase 2 — features make ONE HBM pass total.
// ---------------------------------------------------------------------------
__global__ __launch_bounds__(256) void k_flash(const float* __restrict__ features,
                                               const float* __restrict__ W_f,
                                               const int* __restrict__ lens,
                                               float* __restrict__ part,
                                               float* __restrict__ mbuf,
                                               float* __restrict__ sbuf) {
    const int b    = blockIdx.y;
    const int tile = blockIdx.x;
    const int len  = lens[b];
    const int f0   = tile * FT_;
    if (f0 >= len) return;                        // fully-masked tile: no work
    const int nf   = min(FT_, len - f0);

    __shared__ float s_row[FT_];                  // logits
    __shared__ float sw[FT_];                     // unnormalized exp weights
    const int t    = threadIdx.x;
    const int wave = t >> 6;
    const int lane = t & 63;

    const float4* fb = reinterpret_cast<const float4*>(features + ((size_t)b * F_ + f0) * D_);
    const float4* wp = reinterpret_cast<const float4*>(W_f);

    // ---- phase 1: wave w handles rows w, w+4, ... (8 rows/wave) ----
    for (int f = wave; f < FT_; f += 4) {
        float acc;
        if (f < nf) {
            acc = 0.f;
#pragma unroll
            for (int j = 0; j < 4; ++j) {
                const float4 v = fb[(size_t)f * 256 + lane + 64 * j];
                const float4 w = wp[lane + 64 * j];
                acc = fmaf(v.x, w.x, acc);
                acc = fmaf(v.y, w.y, acc);
                acc = fmaf(v.z, w.z, acc);
                acc = fmaf(v.w, w.w, acc);
            }
#pragma unroll
            for (int off = 32; off; off >>= 1) acc += __shfl_xor(acc, off, 64);
        } else {
            acc = -FLT_MAX;                       // masked row
        }
        if (lane == 0) s_row[f] = acc;
    }
    __syncthreads();

    // ---- local softmax stats (redundant per-thread; LDS broadcast = free) --
    float m = -FLT_MAX;
#pragma unroll
    for (int f = 0; f < FT_; ++f) m = fmaxf(m, s_row[f]);
    if (t < FT_) sw[t] = (t < nf) ? __expf(s_row[t] - m) : 0.f;
    __syncthreads();
    float ssum = 0.f;
#pragma unroll
    for (int f = 0; f < FT_; ++f) ssum += sw[f];

    // ---- phase 2: exp-weighted partial context (tile is L1/L2-resident) ---
    float4 acc = make_float4(0.f, 0.f, 0.f, 0.f);
    for (int f = 0; f < nf; ++f) {
        const float  w = sw[f];
        const float4 v = fb[(size_t)f * 256 + t];
        acc.x = fmaf(w, v.x, acc.x);
        acc.y = fmaf(w, v.y, acc.y);
        acc.z = fmaf(w, v.z, acc.z);
        acc.w = fmaf(w, v.w, acc.w);
    }
    reinterpret_cast<float4*>(part)[((size_t)b * NT_ + tile) * 256 + t] = acc;
    if (t == 0) {
        mbuf[b * NT_ + tile] = m;
        sbuf[b * NT_ + tile] = ssum;
    }
}

// ---------------------------------------------------------------------------
// Kernel 2: global softmax correction + broadcast.
//   M = max_k m_k;  S = sum_k e^{m_k-M} s_k;  ctx = (sum_k e^{m_k-M} part_k)/S
//   out[b, s0..s0+8, :] = ctx.   Grid (8, B_), 256 threads (thread = d-quad).
// ---------------------------------------------------------------------------
__global__ __launch_bounds__(256) void k_combine(const float* __restrict__ part,
                                                 const float* __restrict__ mbuf,
                                                 const float* __restrict__ sbuf,
                                                 const int* __restrict__ lens,
                                                 float* __restrict__ out) {
    const int b  = blockIdx.y;
    const int t  = threadIdx.x;
    const int nt = min(NT_, (lens[b] + FT_ - 1) / FT_);

    __shared__ float fac[NT_];
    // global max over valid tiles (redundant per-thread; L2-cached scalars)
    float M = -FLT_MAX;
    for (int k = 0; k < nt; ++k) M = fmaxf(M, mbuf[b * NT_ + k]);
    if (t < NT_) fac[t] = (t < nt) ? __expf(mbuf[b * NT_ + t] - M) : 0.f;
    __syncthreads();
    float S = 0.f;
    for (int k = 0; k < nt; ++k) S += fac[k] * sbuf[b * NT_ + k];
    const float inv = 1.f / S;

    const float4* pp = reinterpret_cast<const float4*>(part) + (size_t)b * NT_ * 256 + t;
    float4 acc = make_float4(0.f, 0.f, 0.f, 0.f);
    for (int k = 0; k < nt; ++k) {
        const float  f = fac[k];
        const float4 v = pp[(size_t)k * 256];
        acc.x = fmaf(f, v.x, acc.x);
        acc.y = fmaf(f, v.y, acc.y);
        acc.z = fmaf(f, v.z, acc.z);
        acc.w = fmaf(f, v.w, acc.w);
    }
    acc.x *= inv; acc.y *= inv; acc.z *= inv; acc.w *= inv;

    const int s0 = blockIdx.x * 8;
    float4* ob = reinterpret_cast<float4*>(out) + ((size_t)b * S_ + s0) * 256 + t;
#pragma unroll
    for (int s = 0; s < 8; ++s) ob[(size_t)s * 256] = acc;
}

// ---------------------------------------------------------------------------
extern "C" void kernel_launch(void* const* d_in, const int* in_sizes, int n_in,
                              void* d_out, int out_size, void* d_ws, size_t ws_size,
                              hipStream_t stream) {
    (void)in_sizes; (void)n_in; (void)out_size; (void)ws_size;
    // Inputs: sen_emb, features, feature_lens, W, b.
    // sen_emb and b are mathematically irrelevant: softmax over f is invariant
    // to the per-(b,s) additive constant s_emb[b,s] + b0, so attn (and the
    // output) is independent of s -> one ctx row per b, broadcast over s.
    const float* features = (const float*)d_in[1];
    const int*   lens     = (const int*)d_in[2];
    const float* W        = (const float*)d_in[3];
    float*       out      = (float*)d_out;

    float* part = (float*)d_ws;                  // B_*NT_*D_ floats (4 MB)
    float* mbuf = part + (size_t)B_ * NT_ * D_;  // B_*NT_ floats
    float* sbuf = mbuf + B_ * NT_;               // B_*NT_ floats

    k_flash  <<<dim3(NT_, B_), 256, 0, stream>>>(features, W + E_, lens, part, mbuf, sbuf);
    k_combine<<<dim3(8, B_),   256, 0, stream>>>(part, mbuf, sbuf, lens, out);
}